// Round 1
// baseline (1212.565 us; speedup 1.0000x reference)
//
#include <hip/hip_runtime.h>
#include <cstdint>
#include <cstddef>

// Problem constants
#define B_   16
#define N_   576
#define D_   768
#define H_   8
#define HD_  96
#define DF_  3072
#define R_   (B_*N_)               // 9216 rows
#define SCALE_F 0.10206207261596575f  // 96^-0.5

typedef __bf16 bf16;
typedef __attribute__((ext_vector_type(8))) __bf16 bf16x8;
typedef __attribute__((ext_vector_type(4))) float  f32x4;

__device__ __forceinline__ void gld_lds16(const void* g, void* l) {
  __builtin_amdgcn_global_load_lds((const __attribute__((address_space(1))) void*)g,
                                   (__attribute__((address_space(3))) void*)l,
                                   16, 0, 0);
}

// ---------------- prep kernels ----------------
__global__ void cast_f32_bf16_k(const float* __restrict__ x, bf16* __restrict__ y, int n4) {
  int i = blockIdx.x*256 + threadIdx.x;
  if (i >= n4) return;
  float4 v = ((const float4*)x)[i];
  union { bf16 h[4]; unsigned long long q; } u;
  u.h[0] = (bf16)v.x; u.h[1] = (bf16)v.y; u.h[2] = (bf16)v.z; u.h[3] = (bf16)v.w;
  ((unsigned long long*)y)[i] = u.q;
}

// WT[c][r] = (bf16)W[r][c];  rows, cols multiples of 32
__global__ void transpose_cast_k(const float* __restrict__ W, bf16* __restrict__ WT,
                                 int rows, int cols) {
  __shared__ float tile[32][33];
  int cb = blockIdx.x*32, rb = blockIdx.y*32;
  int tx = threadIdx.x, ty = threadIdx.y;   // block (32,8)
  #pragma unroll
  for (int i=0;i<32;i+=8)
    tile[ty+i][tx] = W[(size_t)(rb+ty+i)*cols + cb+tx];
  __syncthreads();
  #pragma unroll
  for (int i=0;i<32;i+=8)
    WT[(size_t)(cb+ty+i)*rows + rb+tx] = (bf16)tile[tx][ty+i];
}

// ---------------- BT-GEMM: C[M,N] = A[M,K] @ Bt[N,K]^T + bias ----------------
// 128x128 tile, BK=64, 256 thr (4 waves 2x2), global_load_lds w=16,
// fragment-linear LDS layout: byte = blk16*2048 + k8*256 + r16*16  (zero bank conflicts)
// EPI: 0 = bf16 out (+bias), 1 = bf16 out in V^T layout [B][D][N], 2 = f32 out, 3 = gelu->bf16
template<int EPI>
__global__ __launch_bounds__(256, 2) void gemm_bt_k(
    const bf16* __restrict__ A, const bf16* __restrict__ Bt,
    const float* __restrict__ bias, float* __restrict__ outF,
    bf16* __restrict__ outB, int M, int Nn, int K)
{
  __shared__ __align__(16) char lds[32768];
  char* As = lds; char* Bs = lds + 16384;
  const int t = threadIdx.x;
  const int lane = t & 63, w = t >> 6, g = lane >> 4, r = lane & 15;
  const int wr = w >> 1, wc = w & 1;
  const int rt = blockIdx.x, ct = blockIdx.y;
  const size_t a0 = (size_t)rt*128, b0 = (size_t)ct*128;

  f32x4 acc[4][4];
  #pragma unroll
  for (int m=0;m<4;++m)
    #pragma unroll
    for (int n=0;n<4;++n) acc[m][n] = (f32x4){0.f,0.f,0.f,0.f};

  // staging decomposition: thread t = (a=t>>7, m=(t>>4)&7, c=t&15)
  const int k8    = (t>>4)&7;
  const int rbase = ((t>>7)<<4) + (t&15);
  const bf16* Abase = A  + (a0 + rbase)*(size_t)K + k8*8;
  const bf16* Bbase = Bt + (b0 + rbase)*(size_t)K + k8*8;
  const size_t rstep = (size_t)32*K;
  const int nkb = K >> 6;

  for (int kb = 0; kb < nkb; ++kb) {
    const size_t ko = (size_t)kb*64;
    #pragma unroll
    for (int i=0;i<4;++i) {
      gld_lds16(Abase + (size_t)i*rstep + ko, As + i*4096 + t*16);
      gld_lds16(Bbase + (size_t)i*rstep + ko, Bs + i*4096 + t*16);
    }
    __syncthreads();   // drains vmcnt before barrier (compiler-emitted)
    #pragma unroll
    for (int kk=0;kk<2;++kk) {
      bf16x8 af[4], bfr[4];
      #pragma unroll
      for (int m=0;m<4;++m) af[m]  = *(const bf16x8*)(As + (wr*4+m)*2048 + kk*1024 + lane*16);
      #pragma unroll
      for (int n=0;n<4;++n) bfr[n] = *(const bf16x8*)(Bs + (wc*4+n)*2048 + kk*1024 + lane*16);
      #pragma unroll
      for (int m=0;m<4;++m)
        #pragma unroll
        for (int n=0;n<4;++n)
          acc[m][n] = __builtin_amdgcn_mfma_f32_16x16x32_bf16(af[m], bfr[n], acc[m][n], 0, 0, 0);
    }
    __syncthreads();
  }

  const int colb = ct*128 + wc*64;
  const int rowb = rt*128 + wr*64;
  #pragma unroll
  for (int n=0;n<4;++n) {
    const int col = colb + n*16 + r;
    const float bc = bias[col];
    #pragma unroll
    for (int m=0;m<4;++m) {
      const int row0 = rowb + m*16 + g*4;
      #pragma unroll
      for (int j=0;j<4;++j) {
        const int row = row0 + j;
        float v = acc[m][n][j] + bc;
        if (EPI == 0) {
          outB[(size_t)row*Nn + col] = (bf16)v;
        } else if (EPI == 1) {          // V^T layout: vt[b][col][n_in_seq]
          const int bb = row / N_, nn = row - bb*N_;
          outB[((size_t)bb*D_ + col)*N_ + nn] = (bf16)v;
        } else if (EPI == 2) {
          outF[(size_t)row*Nn + col] = v;
        } else {                        // exact gelu
          float ge = 0.5f*v*(1.0f + erff(v*0.70710678118f));
          outB[(size_t)row*Nn + col] = (bf16)ge;
        }
      }
    }
  }
  (void)M;
}

// ---------------- fused attention ----------------
// grid (18, H, B), block 128 (2 waves), each wave: 16 q-rows.
// S=0: aout[b,h,q,k]  = 0.5*p     S=1: aout[b,h,k,q] += 0.5*p
template<int S>
__global__ __launch_bounds__(128, 1) void attn_k(
    const bf16* __restrict__ Q, const bf16* __restrict__ Kb,
    const bf16* __restrict__ VT, float* __restrict__ attn_out,
    bf16* __restrict__ obuf)
{
  __shared__ __align__(16) char plds[2*18432];
  const int t = threadIdx.x, w = t>>6, lane = t&63, g = lane>>4, r = lane&15;
  const int qt = blockIdx.x, h = blockIdx.y, b = blockIdx.z;
  const int q0 = qt*32 + w*16;

  // ---- phase 1: S = Q K^T (per wave: 16 rows x 576 cols in 36 accs) ----
  f32x4 s[36];
  #pragma unroll
  for (int n=0;n<36;++n) s[n] = (f32x4){0.f,0.f,0.f,0.f};
  bf16x8 aq[3];
  const bf16* qrow = Q + ((size_t)(b*N_ + q0 + r))*D_ + h*HD_;
  #pragma unroll
  for (int kk=0;kk<3;++kk) aq[kk] = *(const bf16x8*)(qrow + kk*32 + g*8);
  const bf16* kbase = Kb + ((size_t)b*N_ + r)*D_ + h*HD_ + g*8;
  #pragma unroll
  for (int n=0;n<36;++n) {
    const bf16* kr = kbase + (size_t)(n*16)*D_;
    #pragma unroll
    for (int kk=0;kk<3;++kk) {
      bf16x8 bk = *(const bf16x8*)(kr + kk*32);
      s[n] = __builtin_amdgcn_mfma_f32_16x16x32_bf16(aq[kk], bk, s[n], 0, 0, 0);
    }
  }

  // ---- phase 2: softmax (rows spread: lane group g owns rows g*4+j, cols r across tiles)
  float mx[4], rinv[4], sum[4];
  #pragma unroll
  for (int j=0;j<4;++j) {
    float m = -1e30f;
    #pragma unroll
    for (int n=0;n<36;++n) m = fmaxf(m, s[n][j]);
    #pragma unroll
    for (int d=1; d<16; d<<=1) m = fmaxf(m, __shfl_xor(m, d));
    mx[j] = m; sum[j] = 0.f;
  }
  #pragma unroll
  for (int n=0;n<36;++n)
    #pragma unroll
    for (int j=0;j<4;++j) {
      float p = __expf((s[n][j] - mx[j]) * SCALE_F);
      s[n][j] = p; sum[j] += p;
    }
  #pragma unroll
  for (int j=0;j<4;++j) {
    float ss = sum[j];
    #pragma unroll
    for (int d=1; d<16; d<<=1) ss += __shfl_xor(ss, d);
    rinv[j] = 1.0f / ss;
  }

  // ---- phase 3: write attn probs to d_out + stage P (bf16) into LDS ----
  float* aout = attn_out + ((size_t)(b*H_ + h))*N_*N_;
  char* pw = plds + w*18432;   // per-wave region, layout [k8][r16]x16B
  #pragma unroll
  for (int n=0;n<36;++n)
    #pragma unroll
    for (int j=0;j<4;++j) {
      float p = s[n][j]*rinv[j];
      int qr = q0 + g*4 + j, kc = n*16 + r;
      if (S == 0) aout[(size_t)qr*N_ + kc] = 0.5f*p;
      else { float* ap = aout + (size_t)kc*N_ + qr; *ap = *ap + 0.5f*p; }
      *(bf16*)(pw + ((kc>>3)<<8) + ((g*4+j)<<4) + ((kc&7)<<1)) = (bf16)p;
    }
  __syncthreads();

  // ---- phase 4: O = P @ V  (V^T [B][D][N] layout; frags direct from global) ----
  f32x4 oa[6];
  #pragma unroll
  for (int n=0;n<6;++n) oa[n] = (f32x4){0.f,0.f,0.f,0.f};
  const bf16* vtb = VT + ((size_t)b*D_ + h*HD_ + r)*N_ + g*8;
  for (int kt=0; kt<18; ++kt) {
    bf16x8 pa = *(const bf16x8*)(pw + kt*1024 + lane*16);
    #pragma unroll
    for (int n=0;n<6;++n) {
      bf16x8 bv = *(const bf16x8*)(vtb + (size_t)(n*16)*N_ + kt*32);
      oa[n] = __builtin_amdgcn_mfma_f32_16x16x32_bf16(pa, bv, oa[n], 0, 0, 0);
    }
  }
  #pragma unroll
  for (int n=0;n<6;++n)
    #pragma unroll
    for (int j=0;j<4;++j) {
      int qr = q0 + g*4 + j;
      obuf[((size_t)b*N_ + qr)*D_ + h*HD_ + n*16 + r] = (bf16)oa[n][j];
    }
}

// ---------------- LayerNorm: out = LN(xres + y)*gamma + beta ----------------
template<int WRITE16>
__global__ __launch_bounds__(256) void ln_k(
    const float* __restrict__ xres, const float* __restrict__ y,
    const float* __restrict__ gamma, const float* __restrict__ beta,
    float* __restrict__ out32, bf16* __restrict__ out16)
{
  const int w = threadIdx.x>>6, lane = threadIdx.x&63;
  const size_t row = (size_t)blockIdx.x*4 + w;
  const float* xr = xres + row*D_;
  const float* yr = y    + row*D_;
  float v[12]; float s = 0.f, s2 = 0.f;
  #pragma unroll
  for (int i=0;i<3;++i) {
    float4 a  = *(const float4*)(xr + i*256 + lane*4);
    float4 bb = *(const float4*)(yr + i*256 + lane*4);
    float t0=a.x+bb.x, t1=a.y+bb.y, t2=a.z+bb.z, t3=a.w+bb.w;
    v[i*4+0]=t0; v[i*4+1]=t1; v[i*4+2]=t2; v[i*4+3]=t3;
    s  += t0+t1+t2+t3;
    s2 += t0*t0+t1*t1+t2*t2+t3*t3;
  }
  #pragma unroll
  for (int d=1; d<64; d<<=1) { s += __shfl_xor(s, d); s2 += __shfl_xor(s2, d); }
  const float mean = s*(1.f/D_);
  const float var  = s2*(1.f/D_) - mean*mean;
  const float rstd = rsqrtf(var + 1e-5f);
  #pragma unroll
  for (int i=0;i<3;++i) {
    int c = i*256 + lane*4;
    float4 gm = *(const float4*)(gamma + c);
    float4 bt = *(const float4*)(beta  + c);
    float4 o;
    o.x = (v[i*4+0]-mean)*rstd*gm.x + bt.x;
    o.y = (v[i*4+1]-mean)*rstd*gm.y + bt.y;
    o.z = (v[i*4+2]-mean)*rstd*gm.z + bt.z;
    o.w = (v[i*4+3]-mean)*rstd*gm.w + bt.w;
    *(float4*)(out32 + row*D_ + c) = o;
    if (WRITE16) {
      union { bf16 h[4]; unsigned long long q; } u;
      u.h[0]=(bf16)o.x; u.h[1]=(bf16)o.y; u.h[2]=(bf16)o.z; u.h[3]=(bf16)o.w;
      *(unsigned long long*)(out16 + row*D_ + c) = u.q;
    }
  }
}

// ---------------- host ----------------
extern "C" void kernel_launch(void* const* d_in, const int* in_sizes, int n_in,
                              void* d_out, int out_size, void* d_ws, size_t ws_size,
                              hipStream_t stream)
{
  const float* x1  = (const float*)d_in[0];
  const float* x2  = (const float*)d_in[1];
  const float* Wq  = (const float*)d_in[2];  const float* bq  = (const float*)d_in[3];
  const float* Wk  = (const float*)d_in[4];  const float* bk  = (const float*)d_in[5];
  const float* Wv  = (const float*)d_in[6];  const float* bv  = (const float*)d_in[7];
  const float* Wo  = (const float*)d_in[8];  const float* bo  = (const float*)d_in[9];
  const float* g1  = (const float*)d_in[10]; const float* be1 = (const float*)d_in[11];
  const float* g2  = (const float*)d_in[12]; const float* be2 = (const float*)d_in[13];
  const float* W1  = (const float*)d_in[14]; const float* bf1 = (const float*)d_in[15];
  const float* W2  = (const float*)d_in[16]; const float* bf2 = (const float*)d_in[17];

  float* out1 = (float*)d_out;
  float* out2 = out1 + (size_t)R_*D_;
  float* attn = out2 + (size_t)R_*D_;

  // workspace bump allocator (total ~227 MB)
  char* ws = (char*)d_ws;
  size_t off = 0;
  auto alloc = [&](size_t bytes) -> void* {
    void* p = ws + off;
    off += (bytes + 255) & ~(size_t)255;
    return p;
  };
  const size_t RD2 = (size_t)R_*D_*2, RD4 = (size_t)R_*D_*4;
  bf16* xb0  = (bf16*)alloc(RD2);
  bf16* xb1  = (bf16*)alloc(RD2);
  bf16* wqT  = (bf16*)alloc((size_t)D_*D_*2);
  bf16* wkT  = (bf16*)alloc((size_t)D_*D_*2);
  bf16* wvT  = (bf16*)alloc((size_t)D_*D_*2);
  bf16* woT  = (bf16*)alloc((size_t)D_*D_*2);
  bf16* w1T  = (bf16*)alloc((size_t)D_*DF_*2);
  bf16* w2T  = (bf16*)alloc((size_t)DF_*D_*2);
  bf16* Qb   = (bf16*)alloc(RD2);
  bf16* Kbuf = (bf16*)alloc(RD2);
  bf16* VTb  = (bf16*)alloc(RD2);
  bf16* obuf = (bf16*)alloc(RD2);
  float* oproj = (float*)alloc(RD4);      // also reused as FFN output F
  float* h32   = (float*)alloc(RD4);
  bf16*  h16   = (bf16*)alloc(RD2);
  bf16*  G     = (bf16*)alloc((size_t)R_*DF_*2);
  (void)ws_size; (void)in_sizes; (void)n_in; (void)out_size;

  const int n4 = R_*D_/4;
  cast_f32_bf16_k<<<n4/256, 256, 0, stream>>>(x1, xb0, n4);
  cast_f32_bf16_k<<<n4/256, 256, 0, stream>>>(x2, xb1, n4);

  dim3 tb(32,8);
  transpose_cast_k<<<dim3(24,24), tb, 0, stream>>>(Wq, wqT, D_, D_);
  transpose_cast_k<<<dim3(24,24), tb, 0, stream>>>(Wk, wkT, D_, D_);
  transpose_cast_k<<<dim3(24,24), tb, 0, stream>>>(Wv, wvT, D_, D_);
  transpose_cast_k<<<dim3(24,24), tb, 0, stream>>>(Wo, woT, D_, D_);
  transpose_cast_k<<<dim3(96,24), tb, 0, stream>>>(W1, w1T, D_, DF_);   // -> [3072][768]
  transpose_cast_k<<<dim3(24,96), tb, 0, stream>>>(W2, w2T, DF_, D_);   // -> [768][3072]

  const bf16* xb[2] = { xb0, xb1 };
  const float* xf[2] = { x1, x2 };
  float* outp[2] = { out1, out2 };

  for (int s = 0; s < 2; ++s) {
    const bf16* xq  = xb[s];
    const bf16* xkv = xb[1-s];
    // projections
    gemm_bt_k<0><<<dim3(72,6),  256, 0, stream>>>(xq,  wqT, bq, nullptr, Qb,   R_, D_,  D_);
    gemm_bt_k<0><<<dim3(72,6),  256, 0, stream>>>(xkv, wkT, bk, nullptr, Kbuf, R_, D_,  D_);
    gemm_bt_k<1><<<dim3(72,6),  256, 0, stream>>>(xkv, wvT, bv, nullptr, VTb,  R_, D_,  D_);
    // attention (writes attn probs directly to d_out, O to obuf)
    if (s == 0) attn_k<0><<<dim3(18,H_,B_), 128, 0, stream>>>(Qb, Kbuf, VTb, attn, obuf);
    else        attn_k<1><<<dim3(18,H_,B_), 128, 0, stream>>>(Qb, Kbuf, VTb, attn, obuf);
    // output projection
    gemm_bt_k<2><<<dim3(72,6),  256, 0, stream>>>(obuf, woT, bo, oproj, nullptr, R_, D_, D_);
    // h = LN(xq + oproj)
    ln_k<1><<<R_/4, 256, 0, stream>>>(xf[s], oproj, g1, be1, h32, h16);
    // FFN
    gemm_bt_k<3><<<dim3(72,24), 256, 0, stream>>>(h16, w1T, bf1, nullptr, G, R_, DF_, D_);
    gemm_bt_k<2><<<dim3(72,6),  256, 0, stream>>>(G,   w2T, bf2, oproj, nullptr, R_, D_, DF_);
    // out = LN(h + f)
    ln_k<0><<<R_/4, 256, 0, stream>>>(h32, oproj, g2, be2, outp[s], nullptr);
  }
}